// Round 5
// baseline (115.627 us; speedup 1.0000x reference)
//
#include <hip/hip_runtime.h>
#include <math.h>

#define TOKEN_NUMS 2004
#define PAD_IDX    2003
#define B_DIM      32
#define S_DIM      512
#define SP_DIM     510              // S - 2
#define NROWS      (B_DIM * SP_DIM) // 16320
#define NCHUNKS    (NROWS / 64)     // 255
#define ROW_F4     (TOKEN_NUMS / 4) // 501 float4s per row
#define GRID_N     1020             // 4 waves/block * 4 rows/wave * 1020 = 16320

__device__ __forceinline__ void load_row(const float* __restrict__ pred,
                                         int wid, int lane, float4* v)
{
    int b = wid / SP_DIM;
    int s = wid - b * SP_DIM;
    const float4* row = reinterpret_cast<const float4*>(
        pred + (size_t)(b * S_DIM + s) * TOKEN_NUMS);
    #pragma unroll
    for (int k = 0; k < 7; ++k) v[k] = row[lane + 64 * k];
    v[7] = (lane < (ROW_F4 - 448))
         ? row[lane + 448]
         : make_float4(-INFINITY, -INFINITY, -INFINITY, -INFINITY);
}

__device__ __forceinline__ void argmax_row(const float4* v, int lane, int wid,
                                           int* __restrict__ tok)
{
    float best = -INFINITY;
    int   bidx = 0x7fffffff;
    #pragma unroll
    for (int k = 0; k < 8; ++k) {
        int base = (lane + 64 * k) << 2;
        if (v[k].x > best) { best = v[k].x; bidx = base;     }
        if (v[k].y > best) { best = v[k].y; bidx = base + 1; }
        if (v[k].z > best) { best = v[k].z; bidx = base + 2; }
        if (v[k].w > best) { best = v[k].w; bidx = base + 3; }
    }
    #pragma unroll
    for (int off = 32; off >= 1; off >>= 1) {
        float ov = __shfl_xor(best, off);
        int   oi = __shfl_xor(bidx, off);
        if (ov > best || (ov == best && oi < bidx)) { best = ov; bidx = oi; }
    }
    if (lane == 0) tok[wid] = bidx;
}

// Fused: 4 rows per wave, software-pipelined loads; last block does the loss.
__global__ __launch_bounds__(256, 4) void cvl_fused_kernel(
    const float* __restrict__ pred,
    const float* __restrict__ gt_acc,
    const float* __restrict__ gt_steer,
    const int*   __restrict__ gt_rev,
    float*       __restrict__ out,
    int*         __restrict__ tok,
    unsigned int* __restrict__ counter)
{
    __shared__ int   s_cnt[256];       // 255 + pad
    __shared__ int   s_base[256];      // s_base[255] = total
    __shared__ float s_red[3][4];
    __shared__ int   s_last;

    int tid  = (int)threadIdx.x;
    int wv   = tid >> 6;          // 0..3
    int lane = tid & 63;

    // ---------------- Phase 1: 4 rows per wave, pipelined (vA/vB alternate) ----
    int wid0 = ((int)blockIdx.x * 4 + wv) * 4;   // rows wid0 .. wid0+3
    float4 vA[8], vB[8];

    load_row(pred, wid0,     lane, vA);
    load_row(pred, wid0 + 1, lane, vB);
    argmax_row(vA, lane, wid0, tok);
    load_row(pred, wid0 + 2, lane, vA);
    argmax_row(vB, lane, wid0 + 1, tok);
    load_row(pred, wid0 + 3, lane, vB);
    argmax_row(vA, lane, wid0 + 2, tok);
    argmax_row(vB, lane, wid0 + 3, tok);

    // ---------------- Ticket: last block proceeds ----------------
    __syncthreads();
    if (tid == 0) {
        unsigned int t = __hip_atomic_fetch_add(counter, 1u,
                            __ATOMIC_ACQ_REL, __HIP_MEMORY_SCOPE_AGENT);
        s_last = (t == GRID_N - 1) ? 1 : 0;
        s_cnt[255] = 0;
    }
    __syncthreads();
    if (!s_last) return;

    // ---------------- Phase 2 (last block, 4 waves): streaming, register-lean ----
    #pragma unroll 4
    for (int c = wv; c < NCHUNKS; c += 4) {
        int tkc = tok[c * 64 + lane];
        unsigned long long m = __ballot(tkc != PAD_IDX);
        if (lane == 0) s_cnt[c] = __popcll(m);
    }
    __syncthreads();

    if (wv == 0) {  // exact parallel int scan, 4 counts per lane
        int c0 = lane << 2;
        int a0 = s_cnt[c0], a1 = s_cnt[c0+1], a2 = s_cnt[c0+2], a3 = s_cnt[c0+3];
        int ls = a0 + a1 + a2 + a3;
        int incl = ls;
        #pragma unroll
        for (int off = 1; off <= 32; off <<= 1) {
            int u = __shfl_up(incl, off);
            if (lane >= off) incl += u;
        }
        int base = incl - ls;
        s_base[c0]     = base;
        s_base[c0 + 1] = base + a0;
        s_base[c0 + 2] = base + a0 + a1;
        s_base[c0 + 3] = base + a0 + a1 + a2;   // lane63: s_base[255] = total
    }
    __syncthreads();

    float cnt = fmaxf((float)s_base[255], 1.0f);
    const float lse   = log1pf(expf(1.0f));
    const float scale = 1.0f / 9.0f;   // 1/(BASE-1)

    float accAS = 0.0f, accR = 0.0f, ceC = 0.0f;

    #pragma unroll 4
    for (int c = wv; c < NCHUNKS; c += 4) {
        int tkc = tok[c * 64 + lane];
        bool valid = (tkc != PAD_IDX);
        unsigned long long m = __ballot(valid);
        int p = s_base[c] + __popcll(m & ((1ull << lane) - 1ull));
        p = valid ? p : 0;
        float ga = gt_acc[p];
        float gs = gt_steer[p];
        int   gr = gt_rev[p];
        if (valid) {
            int rev = tkc & 1;
            int st  = (tkc >> 1) % 10;
            int bt  = (tkc / 20) % 10;
            int tt  = (tkc / 200) % 10;

            float acc_p   = (float)tt * scale - (float)bt * scale;
            float steer_p = (float)st * scale * 2.0f - 1.0f;

            float d = acc_p - ga;
            float a = fabsf(d);
            accAS += (a < 1.0f) ? 0.5f * d * d : a - 0.5f;

            d = steer_p - gs;
            a = fabsf(d);
            accAS += (a < 1.0f) ? 0.5f * d * d : a - 0.5f;

            if (gr != PAD_IDX) {
                accR += lse - ((rev == gr) ? 1.0f : 0.0f);
                ceC  += 1.0f;
            }
        }
    }

    #pragma unroll
    for (int o = 32; o >= 1; o >>= 1) {
        accAS += __shfl_down(accAS, o);
        accR  += __shfl_down(accR,  o);
        ceC   += __shfl_down(ceC,   o);
    }
    if (lane == 0) { s_red[0][wv] = accAS; s_red[1][wv] = accR; s_red[2][wv] = ceC; }
    __syncthreads();

    if (tid == 0) {
        float rAS = 0.0f, rR = 0.0f, rC = 0.0f;
        #pragma unroll
        for (int w = 0; w < 4; ++w) {
            rAS += s_red[0][w]; rR += s_red[1][w]; rC += s_red[2][w];
        }
        out[0] = rAS / cnt;
        out[1] = rR / fmaxf(rC, 1.0f);
    }
}

extern "C" void kernel_launch(void* const* d_in, const int* in_sizes, int n_in,
                              void* d_out, int out_size, void* d_ws, size_t ws_size,
                              hipStream_t stream)
{
    const float* pred     = (const float*)d_in[0];
    const float* gt_acc   = (const float*)d_in[1];
    const float* gt_steer = (const float*)d_in[2];
    const int*   gt_rev   = (const int*)d_in[3];
    float*       out      = (float*)d_out;
    int*          tok     = (int*)d_ws;                              // 65280 B
    unsigned int* counter = (unsigned int*)((char*)d_ws + NROWS * sizeof(int));

    hipMemsetAsync(counter, 0, sizeof(unsigned int), stream);        // graph-safe
    hipLaunchKernelGGL(cvl_fused_kernel, dim3(GRID_N), dim3(256), 0, stream,
                       pred, gt_acc, gt_steer, gt_rev, out, tok, counter);
}